// Round 1
// baseline (1234.406 us; speedup 1.0000x reference)
//
#include <hip/hip_runtime.h>
#include <math.h>

#define NB   8
#define NPTS 1024
#define PTS  8192      // NB*NPTS
#define KNN  16
#define PK   (PTS*KNN) // 131072

// ---------------- kNN: one block per point; 16x argmin over 1024 dists ----------------
__global__ __launch_bounds__(256) void knn_kernel(const float* __restrict__ pos,
                                                  int* __restrict__ idx,
                                                  float* __restrict__ rel) {
  __shared__ float dist[NPTS];
  __shared__ float rmin[256];
  __shared__ int   rarg[256];
  __shared__ int   nbr[KNN];
  const int i = blockIdx.x;
  const int base = (i >> 10) << 10;
  const int t = threadIdx.x;
  const float pix = pos[3*i], piy = pos[3*i+1], piz = pos[3*i+2];
  const float sqi = pix*pix + piy*piy + piz*piz;
  for (int j = t; j < NPTS; j += 256) {
    const int gj = base + j;
    const float x = pos[3*gj], y = pos[3*gj+1], z = pos[3*gj+2];
    const float sqj = x*x + y*y + z*z;
    const float dt  = pix*x + piy*y + piz*z;
    dist[j] = sqi + sqj - 2.0f*dt;
  }
  __syncthreads();
  for (int s = 0; s < KNN; ++s) {
    float best = INFINITY; int bi = NPTS;
    for (int j = t; j < NPTS; j += 256) {
      const float d = dist[j];
      if (d < best) { best = d; bi = j; }
      else if (d == best && j < bi) { bi = j; }
    }
    rmin[t] = best; rarg[t] = bi;
    __syncthreads();
    for (int off = 128; off > 0; off >>= 1) {
      if (t < off) {
        const float d2 = rmin[t+off]; const int i2 = rarg[t+off];
        if (d2 < rmin[t] || (d2 == rmin[t] && i2 < rarg[t])) { rmin[t] = d2; rarg[t] = i2; }
      }
      __syncthreads();
    }
    if (t == 0) { nbr[s] = rarg[0]; dist[rarg[0]] = INFINITY; }
    __syncthreads();
  }
  if (t < KNN) {
    const int j = base + nbr[t];
    const int r = i*KNN + t;
    idx[r] = j;
    rel[3*r]   = pos[3*j]   - pix;
    rel[3*r+1] = pos[3*j+1] - piy;
    rel[3*r+2] = pos[3*j+2] - piz;
  }
}

// ---------------- conv1 layer1: z1[r][c] = [pj,rel] @ W1 + b1  (64 rows/block) ----------------
__global__ __launch_bounds__(256) void conv1_l1_kernel(const float* __restrict__ pos,
    const int* __restrict__ idx, const float* __restrict__ rel,
    const float* __restrict__ W1, const float* __restrict__ b1,
    float* __restrict__ z1) {
  const int r0 = blockIdx.x * 64;
  const int t = threadIdx.x;
  __shared__ float f[64][6];
  if (t < 64) {
    const int r = r0 + t;
    const int j = idx[r];
    f[t][0] = pos[3*j]; f[t][1] = pos[3*j+1]; f[t][2] = pos[3*j+2];
    f[t][3] = rel[3*r]; f[t][4] = rel[3*r+1]; f[t][5] = rel[3*r+2];
  }
  __syncthreads();
  const int c = t & 63, rg = t >> 6;
  float w[6];
  #pragma unroll
  for (int q = 0; q < 6; ++q) w[q] = W1[q*64 + c];
  const float bb = b1[c];
  for (int j = 0; j < 16; ++j) {
    const int lr = rg + 4*j;
    float z = bb;
    #pragma unroll
    for (int q = 0; q < 6; ++q) z += f[lr][q]*w[q];
    z1[(size_t)(r0+lr)*64 + c] = z;
  }
}

// ---------------- BN stats: two-stage sum/sumsq ----------------
__global__ __launch_bounds__(256) void stats_partial_kernel(const float* __restrict__ z,
    int rowsPerBlock, int C, float* __restrict__ partial) {
  const int t = threadIdx.x;
  const int c = t & (C-1);
  const int rl = t / C;
  const int RL = 256 / C;
  const int r0 = blockIdx.x * rowsPerBlock;
  float s = 0.0f, s2 = 0.0f;
  for (int r = rl; r < rowsPerBlock; r += RL) {
    const float v = z[(size_t)(r0 + r)*C + c];
    s += v; s2 += v*v;
  }
  __shared__ float ls[256], ls2[256];
  ls[t] = s; ls2[t] = s2;
  __syncthreads();
  if (t < C) {
    float a = ls[t], a2 = ls2[t];
    for (int q = 1; q < RL; ++q) { a += ls[t + q*C]; a2 += ls2[t + q*C]; }
    partial[blockIdx.x*2*C + t]     = a;
    partial[blockIdx.x*2*C + C + t] = a2;
  }
}

__global__ __launch_bounds__(256) void stats_final_kernel(const float* __restrict__ partial,
    int G, int C, float invRows,
    const float* __restrict__ gamma, const float* __restrict__ beta,
    float* __restrict__ ss) {
  const int t = threadIdx.x;
  if (t >= C) return;
  float s = 0.0f, s2 = 0.0f;
  for (int g = 0; g < G; ++g) { s += partial[g*2*C + t]; s2 += partial[g*2*C + C + t]; }
  const float mu  = s * invRows;
  const float var = s2 * invRows - mu*mu;
  const float sc  = gamma[t] * rsqrtf(var + 1e-5f);
  ss[t] = sc; ss[C + t] = beta[t] - mu*sc;
}

// ---------------- conv1 layer2 + max over K: one wave per point ----------------
__global__ __launch_bounds__(64) void conv1_l2max_kernel(const float* __restrict__ z1,
    const float* __restrict__ ss, const float* __restrict__ W2,
    const float* __restrict__ b2, float* __restrict__ x1) {
  const int i = blockIdx.x;
  const int t = threadIdx.x;  // channel 0..63
  __shared__ float h[KNN][64];
  const float sc = ss[t], sh = ss[64+t];
  #pragma unroll
  for (int k = 0; k < KNN; ++k) {
    const float z = z1[(size_t)(i*KNN+k)*64 + t];
    h[k][t] = fmaxf(z*sc + sh, 0.0f);
  }
  __syncthreads();
  float w[64];
  #pragma unroll
  for (int d = 0; d < 64; ++d) w[d] = W2[d*64 + t];
  const float bb = b2[t];
  float acc = -INFINITY;
  for (int k = 0; k < KNN; ++k) {
    float y = bb;
    #pragma unroll
    for (int d = 0; d < 64; ++d) y += h[k][d]*w[d];
    acc = fmaxf(acc, y);
  }
  x1[(size_t)i*64 + t] = acc;
}

// ---------------- conv2 layer1: gather x1 + rel -> @W(67x64)+b  (block per point) ----------------
__global__ __launch_bounds__(256) void conv2_l1_kernel(const float* __restrict__ x1,
    const int* __restrict__ idx, const float* __restrict__ rel,
    const float* __restrict__ W, const float* __restrict__ bias,
    float* __restrict__ za) {
  const int i = blockIdx.x;
  const int t = threadIdx.x;
  const int c = t & 63, kg = t >> 6;
  __shared__ float xg[KNN][64];
  __shared__ float rl[KNN][3];
  #pragma unroll
  for (int j = 0; j < 4; ++j) {
    const int k = kg + 4*j;
    const int gj = idx[i*KNN + k];
    xg[k][c] = x1[(size_t)gj*64 + c];
  }
  if (t < KNN*3) rl[t/3][t%3] = rel[i*KNN*3 + t];
  __syncthreads();
  float w[67];
  #pragma unroll
  for (int q = 0; q < 67; ++q) w[q] = W[q*64 + c];
  const float bb = bias[c];
  #pragma unroll
  for (int j = 0; j < 4; ++j) {
    const int k = kg + 4*j;
    float y = bb + rl[k][0]*w[64] + rl[k][1]*w[65] + rl[k][2]*w[66];
    #pragma unroll
    for (int q = 0; q < 64; ++q) y += xg[k][q]*w[q];
    za[(size_t)(i*KNN+k)*64 + c] = y;
  }
}

// ---------------- conv2 layer2: relu(bn(za)) @ W2(64x128)+b2  (128 rows/block) ----------------
__global__ __launch_bounds__(256) void conv2_l2_kernel(const float* __restrict__ za,
    const float* __restrict__ ss, const float* __restrict__ W2,
    const float* __restrict__ b2, float* __restrict__ zb) {
  const int r0 = blockIdx.x * 128;
  const int t = threadIdx.x;
  const int c = t & 127, rg = t >> 7;
  __shared__ float h[128][64];
  for (int q = t; q < 128*64; q += 256) {
    const int lr = q >> 6, f = q & 63;
    const float z = za[(size_t)(r0+lr)*64 + f];
    h[lr][f] = fmaxf(z*ss[f] + ss[64+f], 0.0f);
  }
  __syncthreads();
  float w[64];
  #pragma unroll
  for (int q = 0; q < 64; ++q) w[q] = W2[q*128 + c];
  const float bb = b2[c];
  for (int j = 0; j < 64; ++j) {
    const int lr = rg + 2*j;
    float y = bb;
    #pragma unroll
    for (int q = 0; q < 64; ++q) y += h[lr][q]*w[q];
    zb[(size_t)(r0+lr)*128 + c] = y;
  }
}

// ---------------- conv2 layer3 + max over K (the big one): block per point ----------------
__global__ __launch_bounds__(256) void conv2_l3max_kernel(const float* __restrict__ zb,
    const float* __restrict__ ss, const float* __restrict__ W3,
    const float* __restrict__ b3, float* __restrict__ x2) {
  const int i = blockIdx.x;
  const int t = threadIdx.x;
  __shared__ float h[KNN][128];
  for (int q = t; q < KNN*128; q += 256) {
    const int k = q >> 7, f = q & 127;
    const float z = zb[(size_t)(i*KNN+k)*128 + f];
    h[k][f] = fmaxf(z*ss[f] + ss[128+f], 0.0f);
  }
  __syncthreads();
  float y[64];
  #pragma unroll
  for (int q = 0; q < 64; ++q) y[q] = 0.0f;
  for (int dblk = 0; dblk < 8; ++dblk) {
    float w[64];
    #pragma unroll
    for (int dd = 0; dd < 16; ++dd) {
      #pragma unroll
      for (int jj = 0; jj < 4; ++jj)
        w[dd*4+jj] = W3[(size_t)(dblk*16+dd)*1024 + t + 256*jj];
    }
    #pragma unroll
    for (int k = 0; k < KNN; ++k) {
      #pragma unroll
      for (int dd = 0; dd < 16; ++dd) {
        const float hv = h[k][dblk*16 + dd];
        #pragma unroll
        for (int jj = 0; jj < 4; ++jj)
          y[k*4+jj] += hv * w[dd*4+jj];
      }
    }
  }
  #pragma unroll
  for (int jj = 0; jj < 4; ++jj) {
    const int n = t + 256*jj;
    float m = y[jj];
    #pragma unroll
    for (int k = 1; k < KNN; ++k) m = fmaxf(m, y[k*4+jj]);
    x2[(size_t)i*1024 + n] = m + b3[n];
  }
}

// ---------------- global max pool per graph ----------------
__global__ __launch_bounds__(256) void pool_kernel(const float* __restrict__ x2,
                                                   float* __restrict__ g) {
  const int id = blockIdx.x*256 + threadIdx.x; // 0..8191 = b*1024 + c
  const int b = id >> 10, c = id & 1023;
  const float* p = x2 + (size_t)(b << 10) * 1024 + c;
  float m = -INFINITY;
  for (int n = 0; n < NPTS; ++n) m = fmaxf(m, p[(size_t)n*1024]);
  g[id] = m;
}

// ---------------- final linear (partials over c-quarters) ----------------
__global__ __launch_bounds__(256) void lin_kernel(const float* __restrict__ g,
    const float* __restrict__ W, float* __restrict__ zpart) {
  const int b = blockIdx.x >> 2, q = blockIdx.x & 3;
  const int o = threadIdx.x;
  const float* gb = g + b*1024 + q*256;
  const float* Wq = W + q*256*256;
  float acc = 0.0f;
  for (int c = 0; c < 256; ++c) acc += gb[c] * Wq[c*256 + o];
  zpart[blockIdx.x*256 + o] = acc;
}

// ---------------- final BN(8 rows) + relu ----------------
__global__ __launch_bounds__(256) void final_kernel(const float* __restrict__ zpart,
    const float* __restrict__ lb, const float* __restrict__ lg,
    const float* __restrict__ lbe, float* __restrict__ out) {
  const int o = threadIdx.x;
  float z[NB]; float s = 0.0f, s2 = 0.0f;
  #pragma unroll
  for (int b = 0; b < NB; ++b) {
    float v = lb[o];
    #pragma unroll
    for (int q = 0; q < 4; ++q) v += zpart[(b*4+q)*256 + o];
    z[b] = v; s += v; s2 += v*v;
  }
  const float mu  = s * 0.125f;
  const float var = s2 * 0.125f - mu*mu;
  const float inv = rsqrtf(var + 1e-5f);
  const float sc = lg[o]*inv, sh = lbe[o] - mu*sc;
  #pragma unroll
  for (int b = 0; b < NB; ++b) out[b*256 + o] = fmaxf(z[b]*sc + sh, 0.0f);
}

extern "C" void kernel_launch(void* const* d_in, const int* in_sizes, int n_in,
                              void* d_out, int out_size, void* d_ws, size_t ws_size,
                              hipStream_t stream) {
  const float* pos    = (const float*)d_in[0];
  const float* c1_W1  = (const float*)d_in[2];
  const float* c1_b1  = (const float*)d_in[3];
  const float* c1_g1  = (const float*)d_in[4];
  const float* c1_be1 = (const float*)d_in[5];
  const float* c1_W2  = (const float*)d_in[6];
  const float* c1_b2  = (const float*)d_in[7];
  const float* c2_W1  = (const float*)d_in[8];
  const float* c2_b1  = (const float*)d_in[9];
  const float* c2_g1  = (const float*)d_in[10];
  const float* c2_be1 = (const float*)d_in[11];
  const float* c2_W2  = (const float*)d_in[12];
  const float* c2_b2  = (const float*)d_in[13];
  const float* c2_g2  = (const float*)d_in[14];
  const float* c2_be2 = (const float*)d_in[15];
  const float* c2_W3  = (const float*)d_in[16];
  const float* c2_b3  = (const float*)d_in[17];
  const float* lin_W  = (const float*)d_in[18];
  const float* lin_b  = (const float*)d_in[19];
  const float* lin_g  = (const float*)d_in[20];
  const float* lin_be = (const float*)d_in[21];
  float* out = (float*)d_out;

  char* ws = (char*)d_ws;
  // layout (bytes): idx 512K | rel 1.5M | small | bufA 32M | x1 2M | zb 64M  (~100.3MB total)
  int*   idx     = (int*)  (ws + 0);
  float* rel     = (float*)(ws + 524288);
  float* ss1     = (float*)(ws + 2097152);           // 128
  float* ssA     = (float*)(ws + 2097152 + 512);     // 128
  float* ssB     = (float*)(ws + 2097152 + 1024);    // 256
  float* zpart   = (float*)(ws + 2097152 + 2048);    // 8192
  float* gpool   = (float*)(ws + 2097152 + 2048 + 32768);          // 8192
  float* partial = (float*)(ws + 2097152 + 2048 + 65536);          // 65536 floats
  float* bufA    = (float*)(ws + 2426880);           // 33554432 B (z1 / za / x2)
  float* x1      = (float*)(ws + 35981312);          // 2097152 B
  float* zb      = (float*)(ws + 38078464);          // 67108864 B

  const float invPK = 1.0f / (float)PK;

  knn_kernel<<<PTS, 256, 0, stream>>>(pos, idx, rel);
  conv1_l1_kernel<<<PK/64, 256, 0, stream>>>(pos, idx, rel, c1_W1, c1_b1, bufA);
  stats_partial_kernel<<<256, 256, 0, stream>>>(bufA, PK/256, 64, partial);
  stats_final_kernel<<<1, 256, 0, stream>>>(partial, 256, 64, invPK, c1_g1, c1_be1, ss1);
  conv1_l2max_kernel<<<PTS, 64, 0, stream>>>(bufA, ss1, c1_W2, c1_b2, x1);
  conv2_l1_kernel<<<PTS, 256, 0, stream>>>(x1, idx, rel, c2_W1, c2_b1, bufA);
  stats_partial_kernel<<<256, 256, 0, stream>>>(bufA, PK/256, 64, partial);
  stats_final_kernel<<<1, 256, 0, stream>>>(partial, 256, 64, invPK, c2_g1, c2_be1, ssA);
  conv2_l2_kernel<<<PK/128, 256, 0, stream>>>(bufA, ssA, c2_W2, c2_b2, zb);
  stats_partial_kernel<<<256, 256, 0, stream>>>(zb, PK/256, 128, partial);
  stats_final_kernel<<<1, 256, 0, stream>>>(partial, 256, 128, invPK, c2_g2, c2_be2, ssB);
  conv2_l3max_kernel<<<PTS, 256, 0, stream>>>(zb, ssB, c2_W3, c2_b3, bufA);
  pool_kernel<<<PTS/256, 256, 0, stream>>>(bufA, gpool);
  lin_kernel<<<32, 256, 0, stream>>>(gpool, lin_W, zpart);
  final_kernel<<<1, 256, 0, stream>>>(zpart, lin_b, lin_g, lin_be, out);
}

// Round 3
// 742.623 us; speedup vs baseline: 1.6622x; 1.6622x over previous
//
#include <hip/hip_runtime.h>
#include <math.h>

#define NB   8
#define NPTS 1024
#define PTS  8192      // NB*NPTS
#define KNN  16
#define PK   (PTS*KNN) // 131072

typedef __attribute__((ext_vector_type(8))) _Float16 f16x8;
typedef __attribute__((ext_vector_type(4))) float f32x4;

__device__ __forceinline__ unsigned short f2h(float f) {
  _Float16 h = (_Float16)f;
  union { _Float16 h; unsigned short u; } c; c.h = h;
  return c.u;
}

// ---------------- kNN: one block per point; 16x argmin over 1024 dists ----------------
__global__ __launch_bounds__(256) void knn_kernel(const float* __restrict__ pos,
                                                  int* __restrict__ idx,
                                                  float* __restrict__ rel) {
  __shared__ float dist[NPTS];
  __shared__ float rmin[256];
  __shared__ int   rarg[256];
  __shared__ int   nbr[KNN];
  const int i = blockIdx.x;
  const int base = (i >> 10) << 10;
  const int t = threadIdx.x;
  const float pix = pos[3*i], piy = pos[3*i+1], piz = pos[3*i+2];
  const float sqi = pix*pix + piy*piy + piz*piz;
  for (int j = t; j < NPTS; j += 256) {
    const int gj = base + j;
    const float x = pos[3*gj], y = pos[3*gj+1], z = pos[3*gj+2];
    const float sqj = x*x + y*y + z*z;
    const float dt  = pix*x + piy*y + piz*z;
    dist[j] = sqi + sqj - 2.0f*dt;
  }
  __syncthreads();
  for (int s = 0; s < KNN; ++s) {
    float best = INFINITY; int bi = NPTS;
    for (int j = t; j < NPTS; j += 256) {
      const float d = dist[j];
      if (d < best) { best = d; bi = j; }
      else if (d == best && j < bi) { bi = j; }
    }
    rmin[t] = best; rarg[t] = bi;
    __syncthreads();
    for (int off = 128; off > 0; off >>= 1) {
      if (t < off) {
        const float d2 = rmin[t+off]; const int i2 = rarg[t+off];
        if (d2 < rmin[t] || (d2 == rmin[t] && i2 < rarg[t])) { rmin[t] = d2; rarg[t] = i2; }
      }
      __syncthreads();
    }
    if (t == 0) { nbr[s] = rarg[0]; dist[rarg[0]] = INFINITY; }
    __syncthreads();
  }
  if (t < KNN) {
    const int j = base + nbr[t];
    const int r = i*KNN + t;
    idx[r] = j;
    rel[3*r]   = pos[3*j]   - pix;
    rel[3*r+1] = pos[3*j+1] - piy;
    rel[3*r+2] = pos[3*j+2] - piz;
  }
}

// ---------------- conv1 layer1: z1[r][c] = [pj,rel] @ W1 + b1  (64 rows/block) ----------------
__global__ __launch_bounds__(256) void conv1_l1_kernel(const float* __restrict__ pos,
    const int* __restrict__ idx, const float* __restrict__ rel,
    const float* __restrict__ W1, const float* __restrict__ b1,
    float* __restrict__ z1) {
  const int r0 = blockIdx.x * 64;
  const int t = threadIdx.x;
  __shared__ float f[64][6];
  if (t < 64) {
    const int r = r0 + t;
    const int j = idx[r];
    f[t][0] = pos[3*j]; f[t][1] = pos[3*j+1]; f[t][2] = pos[3*j+2];
    f[t][3] = rel[3*r]; f[t][4] = rel[3*r+1]; f[t][5] = rel[3*r+2];
  }
  __syncthreads();
  const int c = t & 63, rg = t >> 6;
  float w[6];
  #pragma unroll
  for (int q = 0; q < 6; ++q) w[q] = W1[q*64 + c];
  const float bb = b1[c];
  for (int j = 0; j < 16; ++j) {
    const int lr = rg + 4*j;
    float z = bb;
    #pragma unroll
    for (int q = 0; q < 6; ++q) z += f[lr][q]*w[q];
    z1[(size_t)(r0+lr)*64 + c] = z;
  }
}

// ---------------- BN stats: two-stage sum/sumsq ----------------
__global__ __launch_bounds__(256) void stats_partial_kernel(const float* __restrict__ z,
    int rowsPerBlock, int C, float* __restrict__ partial) {
  const int t = threadIdx.x;
  const int c = t & (C-1);
  const int rl = t / C;
  const int RL = 256 / C;
  const int r0 = blockIdx.x * rowsPerBlock;
  float s = 0.0f, s2 = 0.0f;
  for (int r = rl; r < rowsPerBlock; r += RL) {
    const float v = z[(size_t)(r0 + r)*C + c];
    s += v; s2 += v*v;
  }
  __shared__ float ls[256], ls2[256];
  ls[t] = s; ls2[t] = s2;
  __syncthreads();
  if (t < C) {
    float a = ls[t], a2 = ls2[t];
    for (int q = 1; q < RL; ++q) { a += ls[t + q*C]; a2 += ls2[t + q*C]; }
    partial[blockIdx.x*2*C + t]     = a;
    partial[blockIdx.x*2*C + C + t] = a2;
  }
}

__global__ __launch_bounds__(256) void stats_final_kernel(const float* __restrict__ partial,
    int G, int C, float invRows,
    const float* __restrict__ gamma, const float* __restrict__ beta,
    float* __restrict__ ss) {
  const int t = threadIdx.x;
  if (t >= C) return;
  float s = 0.0f, s2 = 0.0f;
  for (int g = 0; g < G; ++g) { s += partial[g*2*C + t]; s2 += partial[g*2*C + C + t]; }
  const float mu  = s * invRows;
  const float var = s2 * invRows - mu*mu;
  const float sc  = gamma[t] * rsqrtf(var + 1e-5f);
  ss[t] = sc; ss[C + t] = beta[t] - mu*sc;
}

// ---------------- conv1 layer2 + max over K: one wave per point ----------------
__global__ __launch_bounds__(64) void conv1_l2max_kernel(const float* __restrict__ z1,
    const float* __restrict__ ss, const float* __restrict__ W2,
    const float* __restrict__ b2, float* __restrict__ x1) {
  const int i = blockIdx.x;
  const int t = threadIdx.x;  // channel 0..63
  __shared__ float h[KNN][64];
  const float sc = ss[t], sh = ss[64+t];
  #pragma unroll
  for (int k = 0; k < KNN; ++k) {
    const float z = z1[(size_t)(i*KNN+k)*64 + t];
    h[k][t] = fmaxf(z*sc + sh, 0.0f);
  }
  __syncthreads();
  float w[64];
  #pragma unroll
  for (int d = 0; d < 64; ++d) w[d] = W2[d*64 + t];
  const float bb = b2[t];
  float acc = -INFINITY;
  for (int k = 0; k < KNN; ++k) {
    float y = bb;
    #pragma unroll
    for (int d = 0; d < 64; ++d) y += h[k][d]*w[d];
    acc = fmaxf(acc, y);
  }
  x1[(size_t)i*64 + t] = acc;
}

// ---------------- conv2 layer1: gather x1 + rel -> @W(67x64)+b  (block per point) ----------------
__global__ __launch_bounds__(256) void conv2_l1_kernel(const float* __restrict__ x1,
    const int* __restrict__ idx, const float* __restrict__ rel,
    const float* __restrict__ W, const float* __restrict__ bias,
    float* __restrict__ za) {
  const int i = blockIdx.x;
  const int t = threadIdx.x;
  const int c = t & 63, kg = t >> 6;
  __shared__ float xg[KNN][64];
  __shared__ float rl[KNN][3];
  #pragma unroll
  for (int j = 0; j < 4; ++j) {
    const int k = kg + 4*j;
    const int gj = idx[i*KNN + k];
    xg[k][c] = x1[(size_t)gj*64 + c];
  }
  if (t < KNN*3) rl[t/3][t%3] = rel[i*KNN*3 + t];
  __syncthreads();
  float w[67];
  #pragma unroll
  for (int q = 0; q < 67; ++q) w[q] = W[q*64 + c];
  const float bb = bias[c];
  #pragma unroll
  for (int j = 0; j < 4; ++j) {
    const int k = kg + 4*j;
    float y = bb + rl[k][0]*w[64] + rl[k][1]*w[65] + rl[k][2]*w[66];
    #pragma unroll
    for (int q = 0; q < 64; ++q) y += xg[k][q]*w[q];
    za[(size_t)(i*KNN+k)*64 + c] = y;
  }
}

// ---------------- conv2 layer2: relu(bn(za)) @ W2(64x128)+b2  (128 rows/block) ----------------
__global__ __launch_bounds__(256) void conv2_l2_kernel(const float* __restrict__ za,
    const float* __restrict__ ss, const float* __restrict__ W2,
    const float* __restrict__ b2, float* __restrict__ zb) {
  const int r0 = blockIdx.x * 128;
  const int t = threadIdx.x;
  const int c = t & 127, rg = t >> 7;
  __shared__ float h[128][64];
  for (int q = t; q < 128*64; q += 256) {
    const int lr = q >> 6, f = q & 63;
    const float z = za[(size_t)(r0+lr)*64 + f];
    h[lr][f] = fmaxf(z*ss[f] + ss[64+f], 0.0f);
  }
  __syncthreads();
  float w[64];
  #pragma unroll
  for (int q = 0; q < 64; ++q) w[q] = W2[q*128 + c];
  const float bb = b2[c];
  for (int j = 0; j < 64; ++j) {
    const int lr = rg + 2*j;
    float y = bb;
    #pragma unroll
    for (int q = 0; q < 64; ++q) y += h[lr][q]*w[q];
    zb[(size_t)(r0+lr)*128 + c] = y;
  }
}

// ---------------- W3 -> fp16 transposed [1024][128] ----------------
__global__ __launch_bounds__(256) void w3t_kernel(const float* __restrict__ W3,
                                                  unsigned short* __restrict__ W3T) {
  const int k = blockIdx.x;           // 0..127
  for (int n = threadIdx.x; n < 1024; n += 256)
    W3T[n*128 + k] = f2h(W3[(size_t)k*1024 + n]);
}

// ---------------- conv2 layer3 + max over K: fp16 MFMA GEMM, fused per-point max ----------------
// grid: 1024 row-blocks (128 rows = 8 points each); loops 8 column-chunks of 128.
// LDS: As/Bs 32KB each, 16B-block XOR swizzle (kblk ^ (row&7)) to kill bank conflicts.
__global__ __launch_bounds__(256, 2) void conv2_l3max_mfma(
    const float* __restrict__ zb, const float* __restrict__ ss,
    const unsigned short* __restrict__ W3T, const float* __restrict__ b3,
    float* __restrict__ x2) {
  __shared__ unsigned short As[128*128];
  __shared__ unsigned short Bs[128*128];
  const int r0 = blockIdx.x * 128;
  const int t = threadIdx.x;
  const int lane = t & 63, w = t >> 6;
  const int quad = lane >> 4, mcol = lane & 15;

  // ---- stage A: relu(bn(zb)) -> fp16, swizzled ----
  {
    const int kb = t & 15;          // 16B block along K (8 halves)
    const int rr = t >> 4;          // 16 rows per pass
    float sc[8], sh[8];
    #pragma unroll
    for (int q = 0; q < 8; ++q) { sc[q] = ss[kb*8 + q]; sh[q] = ss[128 + kb*8 + q]; }
    #pragma unroll
    for (int it = 0; it < 8; ++it) {
      const int r = rr + it*16;
      const float* src = zb + (size_t)(r0 + r)*128 + kb*8;
      const float4 v0 = *(const float4*)(src);
      const float4 v1 = *(const float4*)(src + 4);
      union { unsigned short s[8]; uint4 v; } o;
      o.s[0] = f2h(fmaxf(v0.x*sc[0] + sh[0], 0.0f));
      o.s[1] = f2h(fmaxf(v0.y*sc[1] + sh[1], 0.0f));
      o.s[2] = f2h(fmaxf(v0.z*sc[2] + sh[2], 0.0f));
      o.s[3] = f2h(fmaxf(v0.w*sc[3] + sh[3], 0.0f));
      o.s[4] = f2h(fmaxf(v1.x*sc[4] + sh[4], 0.0f));
      o.s[5] = f2h(fmaxf(v1.y*sc[5] + sh[5], 0.0f));
      o.s[6] = f2h(fmaxf(v1.z*sc[6] + sh[6], 0.0f));
      o.s[7] = f2h(fmaxf(v1.w*sc[7] + sh[7], 0.0f));
      *(uint4*)(As + r*128 + ((kb ^ (r & 7)) * 8)) = o.v;
    }
  }

  const int wrow = (w >> 1) * 64;
  const int wcol = (w & 1) * 64;

  for (int chunk = 0; chunk < 8; ++chunk) {
    const int n0 = chunk * 128;
    __syncthreads();   // A ready (chunk 0) / previous compute done
    // ---- stage B: W3T[n0..n0+128)[0..128) -> LDS, swizzled ----
    {
      const int kb = t & 15, nn = t >> 4;
      #pragma unroll
      for (int it = 0; it < 8; ++it) {
        const int n = nn + it*16;
        const uint4 v = *(const uint4*)(W3T + (size_t)(n0 + n)*128 + kb*8);
        *(uint4*)(Bs + n*128 + ((kb ^ (n & 7)) * 8)) = v;
      }
    }
    __syncthreads();

    f32x4 acc[4][4];
    #pragma unroll
    for (int mi = 0; mi < 4; ++mi)
      #pragma unroll
      for (int ni = 0; ni < 4; ++ni)
        acc[mi][ni] = (f32x4){0.f, 0.f, 0.f, 0.f};

    #pragma unroll
    for (int ks = 0; ks < 4; ++ks) {
      f16x8 af[4], bfr[4];
      #pragma unroll
      for (int mi = 0; mi < 4; ++mi) {
        const int row = wrow + mi*16 + mcol;
        af[mi] = *(const f16x8*)(As + row*128 + (((ks*4 + quad) ^ (row & 7)) * 8));
      }
      #pragma unroll
      for (int ni = 0; ni < 4; ++ni) {
        const int nr = wcol + ni*16 + mcol;
        bfr[ni] = *(const f16x8*)(Bs + nr*128 + (((ks*4 + quad) ^ (nr & 7)) * 8));
      }
      #pragma unroll
      for (int mi = 0; mi < 4; ++mi)
        #pragma unroll
        for (int ni = 0; ni < 4; ++ni)
          acc[mi][ni] = __builtin_amdgcn_mfma_f32_16x16x32_f16(af[mi], bfr[ni], acc[mi][ni], 0, 0, 0);
    }

    // ---- fused max over the 16 rows of each tile (= one point) ----
    #pragma unroll
    for (int mi = 0; mi < 4; ++mi) {
      const int p = blockIdx.x*8 + (w >> 1)*4 + mi;
      #pragma unroll
      for (int ni = 0; ni < 4; ++ni) {
        f32x4 a = acc[mi][ni];
        float m = fmaxf(fmaxf(a[0], a[1]), fmaxf(a[2], a[3]));
        m = fmaxf(m, __shfl_xor(m, 16));
        m = fmaxf(m, __shfl_xor(m, 32));
        if (quad == 0) {
          const int n = n0 + wcol + ni*16 + mcol;
          x2[(size_t)p*1024 + n] = m + b3[n];
        }
      }
    }
  }
}

// ---------------- global max pool, two coalesced stages ----------------
__global__ __launch_bounds__(256) void pool1_kernel(const float* __restrict__ x2,
                                                    float* __restrict__ pmax) {
  const int b = blockIdx.x >> 4, g = blockIdx.x & 15;
  const int t = threadIdx.x;
  const float* base = x2 + (size_t)(b*1024 + g*64)*1024;
  float m0 = -INFINITY, m1 = -INFINITY, m2 = -INFINITY, m3 = -INFINITY;
  for (int n = 0; n < 64; ++n) {
    const float* row = base + (size_t)n*1024;
    m0 = fmaxf(m0, row[t]);
    m1 = fmaxf(m1, row[t + 256]);
    m2 = fmaxf(m2, row[t + 512]);
    m3 = fmaxf(m3, row[t + 768]);
  }
  float* o = pmax + (size_t)blockIdx.x*1024;
  o[t] = m0; o[t+256] = m1; o[t+512] = m2; o[t+768] = m3;
}

__global__ __launch_bounds__(256) void pool2_kernel(const float* __restrict__ pmax,
                                                    float* __restrict__ g) {
  const int id = blockIdx.x*256 + threadIdx.x; // b*1024 + c
  const int b = id >> 10, c = id & 1023;
  float m = -INFINITY;
  for (int q = 0; q < 16; ++q) m = fmaxf(m, pmax[(size_t)(b*16 + q)*1024 + c]);
  g[id] = m;
}

// ---------------- final linear (partials over c-quarters) ----------------
__global__ __launch_bounds__(256) void lin_kernel(const float* __restrict__ g,
    const float* __restrict__ W, float* __restrict__ zpart) {
  const int b = blockIdx.x >> 2, q = blockIdx.x & 3;
  const int o = threadIdx.x;
  const float* gb = g + b*1024 + q*256;
  const float* Wq = W + q*256*256;
  float acc = 0.0f;
  for (int c = 0; c < 256; ++c) acc += gb[c] * Wq[c*256 + o];
  zpart[blockIdx.x*256 + o] = acc;
}

// ---------------- final BN(8 rows) + relu ----------------
__global__ __launch_bounds__(256) void final_kernel(const float* __restrict__ zpart,
    const float* __restrict__ lb, const float* __restrict__ lg,
    const float* __restrict__ lbe, float* __restrict__ out) {
  const int o = threadIdx.x;
  float z[NB]; float s = 0.0f, s2 = 0.0f;
  #pragma unroll
  for (int b = 0; b < NB; ++b) {
    float v = lb[o];
    #pragma unroll
    for (int q = 0; q < 4; ++q) v += zpart[(b*4+q)*256 + o];
    z[b] = v; s += v; s2 += v*v;
  }
  const float mu  = s * 0.125f;
  const float var = s2 * 0.125f - mu*mu;
  const float inv = rsqrtf(var + 1e-5f);
  const float sc = lg[o]*inv, sh = lbe[o] - mu*sc;
  #pragma unroll
  for (int b = 0; b < NB; ++b) out[b*256 + o] = fmaxf(z[b]*sc + sh, 0.0f);
}

extern "C" void kernel_launch(void* const* d_in, const int* in_sizes, int n_in,
                              void* d_out, int out_size, void* d_ws, size_t ws_size,
                              hipStream_t stream) {
  const float* pos    = (const float*)d_in[0];
  const float* c1_W1  = (const float*)d_in[2];
  const float* c1_b1  = (const float*)d_in[3];
  const float* c1_g1  = (const float*)d_in[4];
  const float* c1_be1 = (const float*)d_in[5];
  const float* c1_W2  = (const float*)d_in[6];
  const float* c1_b2  = (const float*)d_in[7];
  const float* c2_W1  = (const float*)d_in[8];
  const float* c2_b1  = (const float*)d_in[9];
  const float* c2_g1  = (const float*)d_in[10];
  const float* c2_be1 = (const float*)d_in[11];
  const float* c2_W2  = (const float*)d_in[12];
  const float* c2_b2  = (const float*)d_in[13];
  const float* c2_g2  = (const float*)d_in[14];
  const float* c2_be2 = (const float*)d_in[15];
  const float* c2_W3  = (const float*)d_in[16];
  const float* c2_b3  = (const float*)d_in[17];
  const float* lin_W  = (const float*)d_in[18];
  const float* lin_b  = (const float*)d_in[19];
  const float* lin_g  = (const float*)d_in[20];
  const float* lin_be = (const float*)d_in[21];
  float* out = (float*)d_out;

  char* ws = (char*)d_ws;
  // layout (bytes): idx 512K | rel 1.5M | small | bufA 32M | x1/W3T 2M | zb 64M
  int*   idx     = (int*)  (ws + 0);
  float* rel     = (float*)(ws + 524288);
  float* ss1     = (float*)(ws + 2097152);           // 128
  float* ssA     = (float*)(ws + 2097152 + 512);     // 128
  float* ssB     = (float*)(ws + 2097152 + 1024);    // 256
  float* zpart   = (float*)(ws + 2097152 + 2048);    // 8192
  float* gpool   = (float*)(ws + 2097152 + 2048 + 32768);          // 8192
  float* partial = (float*)(ws + 2097152 + 2048 + 65536);          // 65536 floats
  float* bufA    = (float*)(ws + 2426880);           // 33554432 B (z1 / za / x2)
  float* x1      = (float*)(ws + 35981312);          // 2097152 B (x1, then W3T)
  unsigned short* W3T = (unsigned short*)(ws + 35981312); // reuses x1 region after conv2_l1
  float* zb      = (float*)(ws + 38078464);          // 67108864 B (zb, then pmax)
  float* pmax    = (float*)(ws + 38078464);          // 512 KB, reuses zb region after l3max

  const float invPK = 1.0f / (float)PK;

  knn_kernel<<<PTS, 256, 0, stream>>>(pos, idx, rel);
  conv1_l1_kernel<<<PK/64, 256, 0, stream>>>(pos, idx, rel, c1_W1, c1_b1, bufA);
  stats_partial_kernel<<<256, 256, 0, stream>>>(bufA, PK/256, 64, partial);
  stats_final_kernel<<<1, 256, 0, stream>>>(partial, 256, 64, invPK, c1_g1, c1_be1, ss1);
  conv1_l2max_kernel<<<PTS, 64, 0, stream>>>(bufA, ss1, c1_W2, c1_b2, x1);
  conv2_l1_kernel<<<PTS, 256, 0, stream>>>(x1, idx, rel, c2_W1, c2_b1, bufA);
  w3t_kernel<<<128, 256, 0, stream>>>(c2_W3, W3T);   // after conv2_l1: x1 region free
  stats_partial_kernel<<<256, 256, 0, stream>>>(bufA, PK/256, 64, partial);
  stats_final_kernel<<<1, 256, 0, stream>>>(partial, 256, 64, invPK, c2_g1, c2_be1, ssA);
  conv2_l2_kernel<<<PK/128, 256, 0, stream>>>(bufA, ssA, c2_W2, c2_b2, zb);
  stats_partial_kernel<<<256, 256, 0, stream>>>(zb, PK/256, 128, partial);
  stats_final_kernel<<<1, 256, 0, stream>>>(partial, 256, 128, invPK, c2_g2, c2_be2, ssB);
  conv2_l3max_mfma<<<PK/128, 256, 0, stream>>>(zb, ssB, W3T, c2_b3, bufA);
  pool1_kernel<<<NB*16, 256, 0, stream>>>(bufA, pmax);
  pool2_kernel<<<PTS/256, 256, 0, stream>>>(pmax, gpool);
  lin_kernel<<<32, 256, 0, stream>>>(gpool, lin_W, zpart);
  final_kernel<<<1, 256, 0, stream>>>(zpart, lin_b, lin_g, lin_be, out);
}

// Round 4
// 681.590 us; speedup vs baseline: 1.8111x; 1.0895x over previous
//
#include <hip/hip_runtime.h>
#include <math.h>

#define NB   8
#define NPTS 1024
#define PTS  8192      // NB*NPTS
#define KNN  16
#define PK   (PTS*KNN) // 131072

typedef __attribute__((ext_vector_type(8))) _Float16 f16x8;
typedef __attribute__((ext_vector_type(4))) float f32x4;

__device__ __forceinline__ unsigned short f2h(float f) {
  _Float16 h = (_Float16)f;
  union { _Float16 h; unsigned short u; } c; c.h = h;
  return c.u;
}

// ---------------- kNN: one WAVE per point; register-resident top-16, barrier-free ----------------
// block = 256 = 4 waves = 4 points (same graph); grid = 2048.
__global__ __launch_bounds__(256) void knn_kernel(const float* __restrict__ pos,
                                                  int* __restrict__ idx,
                                                  float* __restrict__ rel) {
  __shared__ float px[NPTS], py[NPTS], pz[NPTS];
  const int t = threadIdx.x;
  const int wv = t >> 6, lane = t & 63;
  const int b = blockIdx.x;
  const int graph = b >> 8;             // 256 blocks per graph
  const int base = graph << 10;
  for (int j = t; j < NPTS; j += 256) {
    px[j] = pos[3*(base+j)];
    py[j] = pos[3*(base+j)+1];
    pz[j] = pos[3*(base+j)+2];
  }
  __syncthreads();

  const int il = ((b & 255) << 2) + wv; // point index within graph
  const float pix = px[il], piy = py[il], piz = pz[il];
  const float sqi = pix*pix + piy*piy + piz*piz;

  // each lane owns candidates j = q*64 + lane, distances in registers
  float d[16];
  #pragma unroll
  for (int q = 0; q < 16; ++q) {
    const int j = (q << 6) + lane;
    const float x = px[j], y = py[j], z = pz[j];
    const float sqj = x*x + y*y + z*z;
    const float dt  = pix*x + piy*y + piz*z;
    d[q] = sqi + sqj - 2.0f*dt;
  }
  // per-lane running min (smallest q on ties -> smallest global j)
  float mv = d[0]; int mq = 0;
  #pragma unroll
  for (int q = 1; q < 16; ++q) { if (d[q] < mv) { mv = d[q]; mq = q; } }

  int sel = 0;
  for (int s = 0; s < KNN; ++s) {
    float v = mv; int j = (mq << 6) + lane;
    #pragma unroll
    for (int m = 1; m <= 32; m <<= 1) {
      const float v2 = __shfl_xor(v, m);
      const int   j2 = __shfl_xor(j, m);
      if (v2 < v || (v2 == v && j2 < j)) { v = v2; j = j2; }
    }
    if (lane == s) sel = j;           // lane s records the s-th neighbor
    if (lane == (j & 63)) {           // winner lane consumes and rescans
      const int wq = j >> 6;
      #pragma unroll
      for (int q = 0; q < 16; ++q) if (q == wq) d[q] = INFINITY;
      mv = d[0]; mq = 0;
      #pragma unroll
      for (int q = 1; q < 16; ++q) { if (d[q] < mv) { mv = d[q]; mq = q; } }
    }
  }

  if (lane < KNN) {
    const int i = base + il;
    const int r = i*KNN + lane;
    idx[r] = base + sel;
    rel[3*r]   = px[sel] - pix;
    rel[3*r+1] = py[sel] - piy;
    rel[3*r+2] = pz[sel] - piz;
  }
}

// ---------------- conv1 layer1: z1[r][c] = [pj,rel] @ W1 + b1  (64 rows/block) ----------------
__global__ __launch_bounds__(256) void conv1_l1_kernel(const float* __restrict__ pos,
    const int* __restrict__ idx, const float* __restrict__ rel,
    const float* __restrict__ W1, const float* __restrict__ b1,
    float* __restrict__ z1) {
  const int r0 = blockIdx.x * 64;
  const int t = threadIdx.x;
  __shared__ float f[64][6];
  if (t < 64) {
    const int r = r0 + t;
    const int j = idx[r];
    f[t][0] = pos[3*j]; f[t][1] = pos[3*j+1]; f[t][2] = pos[3*j+2];
    f[t][3] = rel[3*r]; f[t][4] = rel[3*r+1]; f[t][5] = rel[3*r+2];
  }
  __syncthreads();
  const int c = t & 63, rg = t >> 6;
  float w[6];
  #pragma unroll
  for (int q = 0; q < 6; ++q) w[q] = W1[q*64 + c];
  const float bb = b1[c];
  for (int j = 0; j < 16; ++j) {
    const int lr = rg + 4*j;
    float z = bb;
    #pragma unroll
    for (int q = 0; q < 6; ++q) z += f[lr][q]*w[q];
    z1[(size_t)(r0+lr)*64 + c] = z;
  }
}

// ---------------- BN stats: two-stage sum/sumsq ----------------
__global__ __launch_bounds__(256) void stats_partial_kernel(const float* __restrict__ z,
    int rowsPerBlock, int C, float* __restrict__ partial) {
  const int t = threadIdx.x;
  const int c = t & (C-1);
  const int rl = t / C;
  const int RL = 256 / C;
  const int r0 = blockIdx.x * rowsPerBlock;
  float s = 0.0f, s2 = 0.0f;
  for (int r = rl; r < rowsPerBlock; r += RL) {
    const float v = z[(size_t)(r0 + r)*C + c];
    s += v; s2 += v*v;
  }
  __shared__ float ls[256], ls2[256];
  ls[t] = s; ls2[t] = s2;
  __syncthreads();
  if (t < C) {
    float a = ls[t], a2 = ls2[t];
    for (int q = 1; q < RL; ++q) { a += ls[t + q*C]; a2 += ls2[t + q*C]; }
    partial[blockIdx.x*2*C + t]     = a;
    partial[blockIdx.x*2*C + C + t] = a2;
  }
}

__global__ __launch_bounds__(256) void stats_final_kernel(const float* __restrict__ partial,
    int G, int C, float invRows,
    const float* __restrict__ gamma, const float* __restrict__ beta,
    float* __restrict__ ss) {
  const int t = threadIdx.x;
  if (t >= C) return;
  float s = 0.0f, s2 = 0.0f;
  for (int g = 0; g < G; ++g) { s += partial[g*2*C + t]; s2 += partial[g*2*C + C + t]; }
  const float mu  = s * invRows;
  const float var = s2 * invRows - mu*mu;
  const float sc  = gamma[t] * rsqrtf(var + 1e-5f);
  ss[t] = sc; ss[C + t] = beta[t] - mu*sc;
}

// ---------------- conv1 layer2 + max over K: one wave per point ----------------
__global__ __launch_bounds__(64) void conv1_l2max_kernel(const float* __restrict__ z1,
    const float* __restrict__ ss, const float* __restrict__ W2,
    const float* __restrict__ b2, float* __restrict__ x1) {
  const int i = blockIdx.x;
  const int t = threadIdx.x;  // channel 0..63
  __shared__ float h[KNN][64];
  const float sc = ss[t], sh = ss[64+t];
  #pragma unroll
  for (int k = 0; k < KNN; ++k) {
    const float z = z1[(size_t)(i*KNN+k)*64 + t];
    h[k][t] = fmaxf(z*sc + sh, 0.0f);
  }
  __syncthreads();
  float w[64];
  #pragma unroll
  for (int d = 0; d < 64; ++d) w[d] = W2[d*64 + t];
  const float bb = b2[t];
  float acc = -INFINITY;
  for (int k = 0; k < KNN; ++k) {
    float y = bb;
    #pragma unroll
    for (int d = 0; d < 64; ++d) y += h[k][d]*w[d];
    acc = fmaxf(acc, y);
  }
  x1[(size_t)i*64 + t] = acc;
}

// ---------------- conv2 layer1: gather x1 + rel -> @W(67x64)+b  (block per point) ----------------
__global__ __launch_bounds__(256) void conv2_l1_kernel(const float* __restrict__ x1,
    const int* __restrict__ idx, const float* __restrict__ rel,
    const float* __restrict__ W, const float* __restrict__ bias,
    float* __restrict__ za) {
  const int i = blockIdx.x;
  const int t = threadIdx.x;
  const int c = t & 63, kg = t >> 6;
  __shared__ float xg[KNN][64];
  __shared__ float rl[KNN][3];
  #pragma unroll
  for (int j = 0; j < 4; ++j) {
    const int k = kg + 4*j;
    const int gj = idx[i*KNN + k];
    xg[k][c] = x1[(size_t)gj*64 + c];
  }
  if (t < KNN*3) rl[t/3][t%3] = rel[i*KNN*3 + t];
  __syncthreads();
  float w[67];
  #pragma unroll
  for (int q = 0; q < 67; ++q) w[q] = W[q*64 + c];
  const float bb = bias[c];
  #pragma unroll
  for (int j = 0; j < 4; ++j) {
    const int k = kg + 4*j;
    float y = bb + rl[k][0]*w[64] + rl[k][1]*w[65] + rl[k][2]*w[66];
    #pragma unroll
    for (int q = 0; q < 64; ++q) y += xg[k][q]*w[q];
    za[(size_t)(i*KNN+k)*64 + c] = y;
  }
}

// ---------------- conv2 layer2: relu(bn(za)) @ W2(64x128)+b2  (128 rows/block) ----------------
__global__ __launch_bounds__(256) void conv2_l2_kernel(const float* __restrict__ za,
    const float* __restrict__ ss, const float* __restrict__ W2,
    const float* __restrict__ b2, float* __restrict__ zb) {
  const int r0 = blockIdx.x * 128;
  const int t = threadIdx.x;
  const int c = t & 127, rg = t >> 7;
  __shared__ float h[128][64];
  for (int q = t; q < 128*64; q += 256) {
    const int lr = q >> 6, f = q & 63;
    const float z = za[(size_t)(r0+lr)*64 + f];
    h[lr][f] = fmaxf(z*ss[f] + ss[64+f], 0.0f);
  }
  __syncthreads();
  float w[64];
  #pragma unroll
  for (int q = 0; q < 64; ++q) w[q] = W2[q*128 + c];
  const float bb = b2[c];
  for (int j = 0; j < 64; ++j) {
    const int lr = rg + 2*j;
    float y = bb;
    #pragma unroll
    for (int q = 0; q < 64; ++q) y += h[lr][q]*w[q];
    zb[(size_t)(r0+lr)*128 + c] = y;
  }
}

// ---------------- W3 -> fp16 transposed [1024][128] ----------------
__global__ __launch_bounds__(256) void w3t_kernel(const float* __restrict__ W3,
                                                  unsigned short* __restrict__ W3T) {
  const int k = blockIdx.x;           // 0..127
  for (int n = threadIdx.x; n < 1024; n += 256)
    W3T[n*128 + k] = f2h(W3[(size_t)k*1024 + n]);
}

// ---------------- conv2 layer3 + max over K: fp16 MFMA GEMM, fused per-point max ----------------
__global__ __launch_bounds__(256, 2) void conv2_l3max_mfma(
    const float* __restrict__ zb, const float* __restrict__ ss,
    const unsigned short* __restrict__ W3T, const float* __restrict__ b3,
    float* __restrict__ x2) {
  __shared__ unsigned short As[128*128];
  __shared__ unsigned short Bs[128*128];
  const int r0 = blockIdx.x * 128;
  const int t = threadIdx.x;
  const int lane = t & 63, w = t >> 6;
  const int quad = lane >> 4, mcol = lane & 15;

  // ---- stage A: relu(bn(zb)) -> fp16, swizzled ----
  {
    const int kb = t & 15;          // 16B block along K (8 halves)
    const int rr = t >> 4;          // 16 rows per pass
    float sc[8], sh[8];
    #pragma unroll
    for (int q = 0; q < 8; ++q) { sc[q] = ss[kb*8 + q]; sh[q] = ss[128 + kb*8 + q]; }
    #pragma unroll
    for (int it = 0; it < 8; ++it) {
      const int r = rr + it*16;
      const float* src = zb + (size_t)(r0 + r)*128 + kb*8;
      const float4 v0 = *(const float4*)(src);
      const float4 v1 = *(const float4*)(src + 4);
      union { unsigned short s[8]; uint4 v; } o;
      o.s[0] = f2h(fmaxf(v0.x*sc[0] + sh[0], 0.0f));
      o.s[1] = f2h(fmaxf(v0.y*sc[1] + sh[1], 0.0f));
      o.s[2] = f2h(fmaxf(v0.z*sc[2] + sh[2], 0.0f));
      o.s[3] = f2h(fmaxf(v0.w*sc[3] + sh[3], 0.0f));
      o.s[4] = f2h(fmaxf(v1.x*sc[4] + sh[4], 0.0f));
      o.s[5] = f2h(fmaxf(v1.y*sc[5] + sh[5], 0.0f));
      o.s[6] = f2h(fmaxf(v1.z*sc[6] + sh[6], 0.0f));
      o.s[7] = f2h(fmaxf(v1.w*sc[7] + sh[7], 0.0f));
      *(uint4*)(As + r*128 + ((kb ^ (r & 7)) * 8)) = o.v;
    }
  }

  const int wrow = (w >> 1) * 64;
  const int wcol = (w & 1) * 64;

  for (int chunk = 0; chunk < 8; ++chunk) {
    const int n0 = chunk * 128;
    __syncthreads();   // A ready (chunk 0) / previous compute done
    // ---- stage B: W3T[n0..n0+128)[0..128) -> LDS, swizzled ----
    {
      const int kb = t & 15, nn = t >> 4;
      #pragma unroll
      for (int it = 0; it < 8; ++it) {
        const int n = nn + it*16;
        const uint4 v = *(const uint4*)(W3T + (size_t)(n0 + n)*128 + kb*8);
        *(uint4*)(Bs + n*128 + ((kb ^ (n & 7)) * 8)) = v;
      }
    }
    __syncthreads();

    f32x4 acc[4][4];
    #pragma unroll
    for (int mi = 0; mi < 4; ++mi)
      #pragma unroll
      for (int ni = 0; ni < 4; ++ni)
        acc[mi][ni] = (f32x4){0.f, 0.f, 0.f, 0.f};

    #pragma unroll
    for (int ks = 0; ks < 4; ++ks) {
      f16x8 af[4], bfr[4];
      #pragma unroll
      for (int mi = 0; mi < 4; ++mi) {
        const int row = wrow + mi*16 + mcol;
        af[mi] = *(const f16x8*)(As + row*128 + (((ks*4 + quad) ^ (row & 7)) * 8));
      }
      #pragma unroll
      for (int ni = 0; ni < 4; ++ni) {
        const int nr = wcol + ni*16 + mcol;
        bfr[ni] = *(const f16x8*)(Bs + nr*128 + (((ks*4 + quad) ^ (nr & 7)) * 8));
      }
      #pragma unroll
      for (int mi = 0; mi < 4; ++mi)
        #pragma unroll
        for (int ni = 0; ni < 4; ++ni)
          acc[mi][ni] = __builtin_amdgcn_mfma_f32_16x16x32_f16(af[mi], bfr[ni], acc[mi][ni], 0, 0, 0);
    }

    // ---- fused max over the 16 rows of each tile (= one point) ----
    #pragma unroll
    for (int mi = 0; mi < 4; ++mi) {
      const int p = blockIdx.x*8 + (w >> 1)*4 + mi;
      #pragma unroll
      for (int ni = 0; ni < 4; ++ni) {
        f32x4 a = acc[mi][ni];
        float m = fmaxf(fmaxf(a[0], a[1]), fmaxf(a[2], a[3]));
        m = fmaxf(m, __shfl_xor(m, 16));
        m = fmaxf(m, __shfl_xor(m, 32));
        if (quad == 0) {
          const int n = n0 + wcol + ni*16 + mcol;
          x2[(size_t)p*1024 + n] = m + b3[n];
        }
      }
    }
  }
}

// ---------------- global max pool, two coalesced stages ----------------
__global__ __launch_bounds__(256) void pool1_kernel(const float* __restrict__ x2,
                                                    float* __restrict__ pmax) {
  const int b = blockIdx.x >> 4, g = blockIdx.x & 15;
  const int t = threadIdx.x;
  const float* base = x2 + (size_t)(b*1024 + g*64)*1024;
  float m0 = -INFINITY, m1 = -INFINITY, m2 = -INFINITY, m3 = -INFINITY;
  for (int n = 0; n < 64; ++n) {
    const float* row = base + (size_t)n*1024;
    m0 = fmaxf(m0, row[t]);
    m1 = fmaxf(m1, row[t + 256]);
    m2 = fmaxf(m2, row[t + 512]);
    m3 = fmaxf(m3, row[t + 768]);
  }
  float* o = pmax + (size_t)blockIdx.x*1024;
  o[t] = m0; o[t+256] = m1; o[t+512] = m2; o[t+768] = m3;
}

__global__ __launch_bounds__(256) void pool2_kernel(const float* __restrict__ pmax,
                                                    float* __restrict__ g) {
  const int id = blockIdx.x*256 + threadIdx.x; // b*1024 + c
  const int b = id >> 10, c = id & 1023;
  float m = -INFINITY;
  for (int q = 0; q < 16; ++q) m = fmaxf(m, pmax[(size_t)(b*16 + q)*1024 + c]);
  g[id] = m;
}

// ---------------- final linear (partials over c-quarters) ----------------
__global__ __launch_bounds__(256) void lin_kernel(const float* __restrict__ g,
    const float* __restrict__ W, float* __restrict__ zpart) {
  const int b = blockIdx.x >> 2, q = blockIdx.x & 3;
  const int o = threadIdx.x;
  const float* gb = g + b*1024 + q*256;
  const float* Wq = W + q*256*256;
  float acc = 0.0f;
  for (int c = 0; c < 256; ++c) acc += gb[c] * Wq[c*256 + o];
  zpart[blockIdx.x*256 + o] = acc;
}

// ---------------- final BN(8 rows) + relu ----------------
__global__ __launch_bounds__(256) void final_kernel(const float* __restrict__ zpart,
    const float* __restrict__ lb, const float* __restrict__ lg,
    const float* __restrict__ lbe, float* __restrict__ out) {
  const int o = threadIdx.x;
  float z[NB]; float s = 0.0f, s2 = 0.0f;
  #pragma unroll
  for (int b = 0; b < NB; ++b) {
    float v = lb[o];
    #pragma unroll
    for (int q = 0; q < 4; ++q) v += zpart[(b*4+q)*256 + o];
    z[b] = v; s += v; s2 += v*v;
  }
  const float mu  = s * 0.125f;
  const float var = s2 * 0.125f - mu*mu;
  const float inv = rsqrtf(var + 1e-5f);
  const float sc = lg[o]*inv, sh = lbe[o] - mu*sc;
  #pragma unroll
  for (int b = 0; b < NB; ++b) out[b*256 + o] = fmaxf(z[b]*sc + sh, 0.0f);
}

extern "C" void kernel_launch(void* const* d_in, const int* in_sizes, int n_in,
                              void* d_out, int out_size, void* d_ws, size_t ws_size,
                              hipStream_t stream) {
  const float* pos    = (const float*)d_in[0];
  const float* c1_W1  = (const float*)d_in[2];
  const float* c1_b1  = (const float*)d_in[3];
  const float* c1_g1  = (const float*)d_in[4];
  const float* c1_be1 = (const float*)d_in[5];
  const float* c1_W2  = (const float*)d_in[6];
  const float* c1_b2  = (const float*)d_in[7];
  const float* c2_W1  = (const float*)d_in[8];
  const float* c2_b1  = (const float*)d_in[9];
  const float* c2_g1  = (const float*)d_in[10];
  const float* c2_be1 = (const float*)d_in[11];
  const float* c2_W2  = (const float*)d_in[12];
  const float* c2_b2  = (const float*)d_in[13];
  const float* c2_g2  = (const float*)d_in[14];
  const float* c2_be2 = (const float*)d_in[15];
  const float* c2_W3  = (const float*)d_in[16];
  const float* c2_b3  = (const float*)d_in[17];
  const float* lin_W  = (const float*)d_in[18];
  const float* lin_b  = (const float*)d_in[19];
  const float* lin_g  = (const float*)d_in[20];
  const float* lin_be = (const float*)d_in[21];
  float* out = (float*)d_out;

  char* ws = (char*)d_ws;
  // layout (bytes): idx 512K | rel 1.5M | small | bufA 32M | x1/W3T 2M | zb 64M
  int*   idx     = (int*)  (ws + 0);
  float* rel     = (float*)(ws + 524288);
  float* ss1     = (float*)(ws + 2097152);           // 128
  float* ssA     = (float*)(ws + 2097152 + 512);     // 128
  float* ssB     = (float*)(ws + 2097152 + 1024);    // 256
  float* zpart   = (float*)(ws + 2097152 + 2048);    // 8192
  float* gpool   = (float*)(ws + 2097152 + 2048 + 32768);          // 8192
  float* partial = (float*)(ws + 2097152 + 2048 + 65536);          // 65536 floats
  float* bufA    = (float*)(ws + 2426880);           // 33554432 B (z1 / za / x2)
  float* x1      = (float*)(ws + 35981312);          // 2097152 B (x1, then W3T)
  unsigned short* W3T = (unsigned short*)(ws + 35981312); // reuses x1 region after conv2_l1
  float* zb      = (float*)(ws + 38078464);          // 67108864 B (zb, then pmax)
  float* pmax    = (float*)(ws + 38078464);          // 512 KB, reuses zb region after l3max

  const float invPK = 1.0f / (float)PK;

  knn_kernel<<<PTS/4, 256, 0, stream>>>(pos, idx, rel);
  conv1_l1_kernel<<<PK/64, 256, 0, stream>>>(pos, idx, rel, c1_W1, c1_b1, bufA);
  stats_partial_kernel<<<256, 256, 0, stream>>>(bufA, PK/256, 64, partial);
  stats_final_kernel<<<1, 256, 0, stream>>>(partial, 256, 64, invPK, c1_g1, c1_be1, ss1);
  conv1_l2max_kernel<<<PTS, 64, 0, stream>>>(bufA, ss1, c1_W2, c1_b2, x1);
  conv2_l1_kernel<<<PTS, 256, 0, stream>>>(x1, idx, rel, c2_W1, c2_b1, bufA);
  w3t_kernel<<<128, 256, 0, stream>>>(c2_W3, W3T);   // after conv2_l1: x1 region free
  stats_partial_kernel<<<256, 256, 0, stream>>>(bufA, PK/256, 64, partial);
  stats_final_kernel<<<1, 256, 0, stream>>>(partial, 256, 64, invPK, c2_g1, c2_be1, ssA);
  conv2_l2_kernel<<<PK/128, 256, 0, stream>>>(bufA, ssA, c2_W2, c2_b2, zb);
  stats_partial_kernel<<<256, 256, 0, stream>>>(zb, PK/256, 128, partial);
  stats_final_kernel<<<1, 256, 0, stream>>>(partial, 256, 128, invPK, c2_g2, c2_be2, ssB);
  conv2_l3max_mfma<<<PK/128, 256, 0, stream>>>(zb, ssB, W3T, c2_b3, bufA);
  pool1_kernel<<<NB*16, 256, 0, stream>>>(bufA, pmax);
  pool2_kernel<<<PTS/256, 256, 0, stream>>>(pmax, gpool);
  lin_kernel<<<32, 256, 0, stream>>>(gpool, lin_W, zpart);
  final_kernel<<<1, 256, 0, stream>>>(zpart, lin_b, lin_g, lin_be, out);
}